// Round 11
// baseline (223.459 us; speedup 1.0000x reference)
//
#include <hip/hip_runtime.h>
#include <cstdint>
#include <math.h>

#define B 8
#define L 2048
#define D 256
#define H 128

typedef __attribute__((ext_vector_type(8))) _Float16 half8;
typedef __attribute__((ext_vector_type(2))) _Float16 half2v;
typedef __attribute__((ext_vector_type(4))) float f32x4;
typedef unsigned short ushort;
typedef unsigned int uint;

// Layouts:
//  pq/pk (B*L*H fp16) packed MFMA-frag blocks: block=(grow/16)*4+h/32,
//     elem=((h>>3)&3)*128+(grow&15)*8+(h&7)   [proven R4-R6]
//  vt (B*L*D fp16): block=((b*L+key)/32)*16+d/16, elem=((key&31)>>3)*128+(d&15)*8+(key&7)
// R11: pre_kernel v2 — proj role keeps A in REGISTERS (no Af LDS, no extra
// barrier; a[db][j] = A[r0+w*16+l15][db*32+quad*8+j], proven equivalent to
// the Af mapping), W packed inline to 32KB LDS, epilogue S-bounce reuses Wl
// after a barrier. Union LDS 64KB->32KB, launch_bounds (256,2)->(256,4):
// 4 blocks/CU for ALL pre roles. attn_fused = R6 exact (proven 113-115us).
// Dispatch: bid%3==0 -> proj (1024), bid%3 in {1,2} -> vtrans (2048),
// bid>=3072 -> mask (32).
// ---------------------------------------------------------------------------
__launch_bounds__(256, 4)
__global__ void pre_kernel(const float* __restrict__ queries,
                           const float* __restrict__ keys,
                           const float* __restrict__ Wq,
                           const float* __restrict__ Wk,
                           const float* __restrict__ scaling,
                           const void* __restrict__ raw0,
                           const void* __restrict__ raw1,
                           const float* __restrict__ v1,
                           const float* __restrict__ v2,
                           _Float16* __restrict__ pqo,
                           _Float16* __restrict__ pko,
                           _Float16* __restrict__ vt1,
                           _Float16* __restrict__ vt2,
                           float* __restrict__ fb1,
                           float* __restrict__ fb2) {
    __shared__ __attribute__((aligned(16))) union {
        _Float16 Wl[32 * 512];     // proj: 32 KB (also reused as S-bounce)
        float lt[64][65];          // vtrans: 16.6 KB
    } sh;
    __shared__ int flag;

    const int bid = blockIdx.x;
    const int t = threadIdx.x;

    if (bid < 3072 && (bid % 3) == 0) {
        // ----------------- proj role: idx in [0,1024) -----------------
        const int idx = bid / 3;
        const int w = t >> 6;
        const int lane = t & 63;
        const int l15 = lane & 15;
        const int quad = lane >> 4;
        const int z = idx >> 9;
        const int half = (idx >> 8) & 1;
        const int r0 = (idx & 255) * 64;
        const float* in = z ? keys : queries;
        const float* Wsrc = z ? Wk : Wq;
        _Float16* outp = z ? pko : pqo;
        _Float16* Wl = sh.Wl;

        // inline W pack: rows h = half*64 .. +63, 2048 chunks, 8/thread
#pragma unroll
        for (int i = 0; i < 8; ++i) {
            const int cl = t + 256 * i;
            const int hl = cl >> 5;            // 0..63
            const int d0 = (cl & 31) * 8;
            const float* wp = Wsrc + (size_t)(half * 64 + hl) * 256 + d0;
            float4 v0 = *(const float4*)wp;
            float4 v1w = *(const float4*)(wp + 4);
            half8 hv;
            hv[0] = (_Float16)v0.x; hv[1] = (_Float16)v0.y;
            hv[2] = (_Float16)v0.z; hv[3] = (_Float16)v0.w;
            hv[4] = (_Float16)v1w.x; hv[5] = (_Float16)v1w.y;
            hv[6] = (_Float16)v1w.z; hv[7] = (_Float16)v1w.w;
            const int db = d0 >> 5, dq = (d0 >> 3) & 3;
            *(half8*)(Wl + ((hl >> 4) * 8 + db) * 512 + dq * 128 + (hl & 15) * 8) = hv;
        }

        // A-frags straight to registers (no LDS round-trip, no barrier):
        // a[db][j] = A[r0 + w*16 + l15][db*32 + quad*8 + j]
        half8 a[8];
        {
            const float* arow = in + (size_t)(r0 + w * 16 + l15) * 256 + quad * 8;
#pragma unroll
            for (int db = 0; db < 8; ++db) {
                float4 v0 = *(const float4*)(arow + db * 32);
                float4 v1a = *(const float4*)(arow + db * 32 + 4);
                half8 hv;
                hv[0] = (_Float16)v0.x; hv[1] = (_Float16)v0.y;
                hv[2] = (_Float16)v0.z; hv[3] = (_Float16)v0.w;
                hv[4] = (_Float16)v1a.x; hv[5] = (_Float16)v1a.y;
                hv[6] = (_Float16)v1a.z; hv[7] = (_Float16)v1a.w;
                a[db] = hv;
            }
        }
        __syncthreads();   // Wl ready

        f32x4 acc[4];
#pragma unroll
        for (int hti = 0; hti < 4; ++hti) acc[hti] = (f32x4){0.f, 0.f, 0.f, 0.f};
#pragma unroll
        for (int db = 0; db < 8; ++db)
#pragma unroll
            for (int hti = 0; hti < 4; ++hti) {
                half8 bfrag = *(const half8*)(Wl + (hti * 8 + db) * 512 + lane * 8);
                acc[hti] = __builtin_amdgcn_mfma_f32_16x16x32_f16(a[db], bfrag, acc[hti], 0, 0, 0);
            }

        __syncthreads();   // all waves done reading Wl; reuse as S-bounce
        _Float16* S = Wl + w * 1024;   // 1024 halfs per wave
#pragma unroll
        for (int hti = 0; hti < 4; ++hti) {
            const int hl_ = hti * 16 + l15;
            const int hb = hl_ >> 5, hq = (hl_ >> 3) & 3, e = hl_ & 7;
            const float scl = z ? scaling[half * 64 + hl_] : 1.f;
#pragma unroll
            for (int r = 0; r < 4; ++r) {
                float v = fmaxf(acc[hti][r], 0.f) * scl;
                S[hb * 512 + hq * 128 + (quad * 4 + r) * 8 + e] = (_Float16)v;
            }
        }
        const size_t grow16 = (size_t)(r0 >> 4) + w;
        _Float16* gout = outp + (grow16 * 4 + half * 2) * 512;
#pragma unroll
        for (int hb = 0; hb < 2; ++hb) {
            half8 vv = *(const half8*)(S + hb * 512 + lane * 8);
            *(half8*)(gout + hb * 512 + lane * 8) = vv;
        }
    } else if (bid < 3072) {
        // ----------------- vtrans role: idx in [0,2048) -----------------
        const int idx = (bid / 3) * 2 + (bid % 3) - 1;
        const int zz = idx >> 7;          // 0..15: b = zz&7, which = zz>>3
        const int b = zz & 7;
        const int which = zz >> 3;
        const int x = idx & 31;
        const int y = (idx >> 5) & 3;
        const float* src = (which ? v2 : v1) + (size_t)b * L * D;
        _Float16* dst = which ? vt2 : vt1;
        const int k0 = x * 64;
        const int d0 = y * 64;
#pragma unroll
        for (int p = 0; p < 4; ++p) {
            int kr = p * 16 + (t >> 4);
            float4 v = *(const float4*)(src + (size_t)(k0 + kr) * D + d0 + (t & 15) * 4);
            sh.lt[(t & 15) * 4 + 0][kr] = v.x;
            sh.lt[(t & 15) * 4 + 1][kr] = v.y;
            sh.lt[(t & 15) * 4 + 2][kr] = v.z;
            sh.lt[(t & 15) * 4 + 3][kr] = v.w;
        }
        __syncthreads();
        const int d = t & 63;
        const int kk = (t >> 6) & 1;
        const int qp = t >> 7;
        const size_t tile = ((size_t)b * L + k0) / 32 + kk;
        const int ct = (d0 + d) >> 4;
        _Float16* base = dst + (tile * 16 + ct) * 512 + (d & 15) * 8;
#pragma unroll
        for (int s = 0; s < 2; ++s) {
            const int qv = qp * 2 + s;
            const float* lr = &sh.lt[d][kk * 32 + qv * 8];
            half8 hv;
#pragma unroll
            for (int e = 0; e < 8; ++e) hv[e] = (_Float16)lr[e];
            *(half8*)(base + qv * 128) = hv;
        }
    } else {
        // ----------------- mask->bias role: idx in [0,32) -----------------
        const int idx = bid - 3072;
        const int x = idx & 15;
        const int z = idx >> 4;
        const void* raw = z ? raw1 : raw0;
        float* outb = z ? fb2 : fb1;
        const uint* wd = (const uint*)raw;
        if (t == 0) flag = 0;
        __syncthreads();
        if (wd[t] > 1u) flag = 1;   // byte-bool layout iff some word >1
        __syncthreads();
        const int base = x * 1024;
        if (flag) {
            const uint8_t* by = (const uint8_t*)raw;
#pragma unroll
            for (int j = 0; j < 4; ++j) {
                int i = base + t + 256 * j;
                outb[i] = by[i] ? -INFINITY : 0.f;
            }
        } else {
#pragma unroll
            for (int j = 0; j < 4; ++j) {
                int i = base + t + 256 * j;
                outb[i] = wd[i] ? -INFINITY : 0.f;
            }
        }
    }
}

// ---------------------------------------------------------------------------
// attn_fused (R6 exact, proven 113-115us): score + online softmax + PV.
// Block = 64 out-rows (4 waves x 16), key-tiles of 32, double-buffered LDS.
// Grid (L/64, B, 2), block 256.
// ---------------------------------------------------------------------------
__launch_bounds__(256, 2)
__global__ void attn_fused_kernel(const _Float16* __restrict__ pqw,
                                  const _Float16* __restrict__ pkw,
                                  const float* __restrict__ fb1,
                                  const float* __restrict__ fb2,
                                  const _Float16* __restrict__ vt1,
                                  const _Float16* __restrict__ vt2,
                                  float* __restrict__ out) {
    const int t = threadIdx.x;
    const int w = t >> 6;
    const int lane = t & 63;
    const int l15 = lane & 15;
    const int quad = lane >> 4;
    const int bb = blockIdx.y;
    const int z = blockIdx.z;
    const int r0 = blockIdx.x * 64;
    const size_t bL = (size_t)bb * L;

    const _Float16* Qp = z ? pkw : pqw;   // rows side
    const _Float16* Kp = z ? pqw : pkw;   // inner (reduction) side
    const _Float16* Vp = z ? vt2 : vt1;
    const float* fbb = (z ? fb2 : fb1) + bL;
    float* O = out + (z ? (size_t)B * L * D : 0);

    __shared__ __attribute__((aligned(16))) _Float16 klds[2][4096];   // 16 KB
    __shared__ __attribute__((aligned(16))) _Float16 vlds[2][8192];   // 32 KB
    __shared__ __attribute__((aligned(16))) _Float16 plds[4][512];    //  4 KB

    auto stage = [&](int it, int buf) {
        const _Float16* ksrc = Kp + ((bL + it * 32) >> 4) * 2048;
#pragma unroll
        for (int i = 0; i < 2; ++i) {
            const int c = w * 2 + i;
            __builtin_amdgcn_global_load_lds(
                (const __attribute__((address_space(1))) uint*)(ksrc + c * 512 + lane * 8),
                (__attribute__((address_space(3))) uint*)(&klds[buf][c * 512] + lane * 8),
                16, 0, 0);
        }
        const _Float16* vsrc = Vp + ((bL + it * 32) >> 5) * (size_t)8192;
#pragma unroll
        for (int i = 0; i < 4; ++i) {
            const int c = w * 4 + i;
            __builtin_amdgcn_global_load_lds(
                (const __attribute__((address_space(1))) uint*)(vsrc + c * 512 + lane * 8),
                (__attribute__((address_space(3))) uint*)(&vlds[buf][c * 512] + lane * 8),
                16, 0, 0);
        }
    };

    // Q fragments for this wave's 16 rows (rows r0+w*16 .. +15)
    half8 aq[4];
    {
        const _Float16* qb = Qp + ((bL + r0 + w * 16) >> 4) * 2048 + lane * 8;
#pragma unroll
        for (int hb = 0; hb < 4; ++hb) aq[hb] = *(const half8*)(qb + hb * 512);
    }

    stage(0, 0);
    float4 bc0 = *(const float4*)(fbb + quad * 4);
    float4 bc1 = *(const float4*)(fbb + 16 + quad * 4);
    stage(1, 1);

    asm volatile("s_waitcnt vmcnt(6)" ::: "memory");
    __builtin_amdgcn_sched_barrier(0);
    __builtin_amdgcn_s_barrier();
    __builtin_amdgcn_sched_barrier(0);

    f32x4 acc[16];
#pragma unroll
    for (int ct = 0; ct < 16; ++ct) acc[ct] = (f32x4){0.f, 0.f, 0.f, 0.f};
    float lsum = 0.f;
    float m = -1e30f;

    const int NT = 64;
#pragma unroll 2
    for (int it = 0; it < NT; ++it) {
        const int buf = it & 1;

        float4 bn0 = bc0, bn1 = bc1;
        if (it + 1 < NT) {
            bn0 = *(const float4*)(fbb + (it + 1) * 32 + quad * 4);
            bn1 = *(const float4*)(fbb + (it + 1) * 32 + 16 + quad * 4);
        }

        // S^T = K-tile x Q: s[mt][r] = S^T[key=mt*16+quad*4+r][q=l15]
        f32x4 s0 = (f32x4){0.f, 0.f, 0.f, 0.f};
        f32x4 s1 = (f32x4){0.f, 0.f, 0.f, 0.f};
#pragma unroll
        for (int hb = 0; hb < 4; ++hb) {
            half8 kf0 = *(const half8*)(&klds[buf][hb * 512 + lane * 8]);
            half8 kf1 = *(const half8*)(&klds[buf][2048 + hb * 512 + lane * 8]);
            s0 = __builtin_amdgcn_mfma_f32_16x16x32_f16(kf0, aq[hb], s0, 0, 0, 0);
            s1 = __builtin_amdgcn_mfma_f32_16x16x32_f16(kf1, aq[hb], s1, 0, 0, 0);
        }
        float sv0[4], sv1[4];
        float mt_ = -INFINITY;
#pragma unroll
        for (int r = 0; r < 4; ++r) {
            sv0[r] = s0[r] + ((const float*)&bc0)[r];
            sv1[r] = s1[r] + ((const float*)&bc1)[r];
            mt_ = fmaxf(mt_, fmaxf(sv0[r], sv1[r]));
        }
        mt_ = fmaxf(mt_, __shfl_xor(mt_, 16));
        mt_ = fmaxf(mt_, __shfl_xor(mt_, 32));

        if (!__all(mt_ <= m + 8.f)) {
            float mn = fmaxf(m, mt_);
            float sc = __expf(m - mn);
            m = mn;
            lsum *= sc;
#pragma unroll
            for (int ct = 0; ct < 16; ++ct) acc[ct] *= sc;
        }

        float psum = 0.f;
        float p0[4], p1[4];
#pragma unroll
        for (int r = 0; r < 4; ++r) {
            p0[r] = __expf(sv0[r] - m);
            p1[r] = __expf(sv1[r] - m);
            psum += p0[r] + p1[r];
        }
        lsum += psum;
        half2v q00; q00[0] = (_Float16)p0[0]; q00[1] = (_Float16)p0[1];
        half2v q01; q01[0] = (_Float16)p0[2]; q01[1] = (_Float16)p0[3];
        half2v q10; q10[0] = (_Float16)p1[0]; q10[1] = (_Float16)p1[1];
        half2v q11; q11[0] = (_Float16)p1[2]; q11[1] = (_Float16)p1[3];
        _Float16* pw = &plds[w][0];
        const int eb0 = (quad >> 1) * 128 + l15 * 8 + (quad & 1) * 4;
        const int eb1 = (2 + (quad >> 1)) * 128 + l15 * 8 + (quad & 1) * 4;
        *(half2v*)(pw + eb0) = q00;
        *(half2v*)(pw + eb0 + 2) = q01;
        *(half2v*)(pw + eb1) = q10;
        *(half2v*)(pw + eb1 + 2) = q11;
        half8 pfrag = *(const half8*)(pw + lane * 8);   // wave-local RAW

        // PV: out^T[d][q] += V^T x P^T
#pragma unroll
        for (int ct = 0; ct < 16; ++ct) {
            half8 vf = *(const half8*)(&vlds[buf][ct * 512 + lane * 8]);
            acc[ct] = __builtin_amdgcn_mfma_f32_16x16x32_f16(vf, pfrag, acc[ct], 0, 0, 0);
        }

        bc0 = bn0; bc1 = bn1;

        if (it < NT - 1) {
            __builtin_amdgcn_s_barrier();
            __builtin_amdgcn_sched_barrier(0);
            if (it + 2 < NT) {
                stage(it + 2, buf);
                asm volatile("s_waitcnt vmcnt(6)" ::: "memory");
            } else {
                asm volatile("s_waitcnt vmcnt(0)" ::: "memory");
            }
            __builtin_amdgcn_sched_barrier(0);
            __builtin_amdgcn_s_barrier();
            __builtin_amdgcn_sched_barrier(0);
        }
    }

    lsum += __shfl_xor(lsum, 16);
    lsum += __shfl_xor(lsum, 32);
    const float inv = (lsum > 0.f) ? (1.f / lsum) : 0.f;

    const int qrow = r0 + w * 16 + l15;
    float* orow = O + (bL + qrow) * (size_t)D + quad * 4;
#pragma unroll
    for (int ct = 0; ct < 16; ++ct) {
        f32x4 v = acc[ct] * inv;
        *(f32x4*)(orow + ct * 16) = v;
    }
}

extern "C" void kernel_launch(void* const* d_in, const int* in_sizes, int n_in,
                              void* d_out, int out_size, void* d_ws, size_t ws_size,
                              hipStream_t stream) {
    const float* queries  = (const float*)d_in[0];
    const float* keys     = (const float*)d_in[1];
    const float* values_1 = (const float*)d_in[2];
    const void*  v1_mask  = d_in[3];
    const float* values_2 = (const float*)d_in[4];
    const void*  v2_mask  = d_in[5];
    const float* Wq       = (const float*)d_in[6];
    const float* Wk       = (const float*)d_in[7];
    const float* scaling  = (const float*)d_in[8];
    float* out = (float*)d_out;

    _Float16* pqw = (_Float16*)d_ws;                       // B*L*H   (4 MB)
    _Float16* pkw = pqw + (size_t)B * L * H;               // 4 MB
    _Float16* vt1 = pkw + (size_t)B * L * H;               // B*L*D   (8 MB)
    _Float16* vt2 = vt1 + (size_t)B * L * D;               // 8 MB
    float* fb1   = (float*)(vt2 + (size_t)B * L * D);      // 64 KB
    float* fb2   = fb1 + B * L;                            // 64 KB

    pre_kernel<<<3104, 256, 0, stream>>>(
        queries, keys, Wq, Wk, scaling, v1_mask, v2_mask,
        values_1, values_2, pqw, pkw, vt1, vt2, fb1, fb2);
    attn_fused_kernel<<<dim3(L / 64, B, 2), 256, 0, stream>>>(
        pqw, pkw, fb1, fb2, vt1, vt2, out);
}